// Round 2
// baseline (6368.874 us; speedup 1.0000x reference)
//
#include <hip/hip_runtime.h>
#include <math.h>

// ---------------- constants ----------------
constexpr int ROWS_PER_B = 12 * 1024;    // rows (b,t,n) per batch element

// ---------------- graph workspace (float offsets, < 524288) ----------------
constexpr size_t F_N1 = 0;              // 1024*40
constexpr size_t F_N2 = 40960;
constexpr size_t F_ANVAL = 81920;       // 1024*11
constexpr size_t F_ROWVAL = 93184;      // 1024*10
constexpr size_t F_COLSUM = 103424;     // 1024
constexpr size_t F_INVCS = 104448;      // 1024
constexpr size_t F_ATVAL = 105472;      // 10240
constexpr size_t I_ANIDX = 115712;      // ints stored in float slots
constexpr size_t I_ROWIDX = 126976;
constexpr size_t I_COLCNT = 137216;
constexpr size_t I_COLOFF = 138240;     // 1025
constexpr size_t I_COLFILL = 139265;
constexpr size_t I_ATIDX = 140289;      // ends 150529 < 524288
constexpr size_t GRAPH_FLOATS = 524288;

// per-chunk float counts (per batch element)
constexpr size_t PB_GATED = (size_t)ROWS_PER_B * 128;   // 1572864
constexpr size_t PB_HD = (size_t)ROWS_PER_B * 64;       // 786432
constexpr size_t PB_XS = (size_t)32 * 1024 * 64;        // 2097152
constexpr size_t PB_MIX = (size_t)32 * 1024 * 256;      // 8388608
constexpr size_t PB_TOTAL = PB_GATED + PB_HD + 3 * PB_XS + PB_MIX; // 17039360

// ---------------- graph kernels ----------------

__global__ void k_init(int* cnt, int* fill, float* csum) {
    int t = blockIdx.x * 256 + threadIdx.x;
    if (t < 1024) { cnt[t] = 0; fill[t] = 0; csum[t] = 0.f; }
}

__global__ void k_embed(const float* e1, const float* e2, const float* w1, const float* b1,
                        const float* w2, const float* b2, float* n1, float* n2) {
    int idx = blockIdx.x * 256 + threadIdx.x;   // < 81920
    if (idx >= 81920) return;
    int m = idx / 40960, rem = idx - m * 40960;
    int i = rem / 40, j = rem - i * 40;
    const float* e = m ? e2 : e1;
    const float* w = m ? w2 : w1;
    const float* bv = m ? b2 : b1;
    float a = bv[j];
    for (int k = 0; k < 40; k++) a += e[i * 40 + k] * w[k * 40 + j];
    (m ? n2 : n1)[i * 40 + j] = tanhf(3.0f * a);
}

__global__ __launch_bounds__(256) void k_adj(const float* n1, const float* n2,
        float* aN_val, int* aN_idx, float* row_val, int* row_idx,
        int* col_cnt, float* col_sum) {
    __shared__ float arow[1024];
    __shared__ float n1v[40], n2v[40];
    __shared__ float rv[256];
    __shared__ int ri[256];
    __shared__ float topv[10];
    __shared__ int topi[10];
    int v = blockIdx.x, t = threadIdx.x;
    if (t < 40) { n1v[t] = n1[v * 40 + t]; n2v[t] = n2[v * 40 + t]; }
    __syncthreads();
    for (int j = t; j < 1024; j += 256) {
        float d1 = 0.f, d2 = 0.f;
        for (int k = 0; k < 40; k++) {
            d1 += n1v[k] * n2[j * 40 + k];
            d2 += n2v[k] * n1[j * 40 + k];
        }
        float a = tanhf(3.0f * (d1 - d2));
        arow[j] = a > 0.f ? a : 0.f;
    }
    __syncthreads();
    for (int r = 0; r < 10; r++) {
        float bv = -1.f; int bi = 1 << 30;
        for (int j = t; j < 1024; j += 256) {
            float x = arow[j];
            if (x > bv || (x == bv && j < bi)) { bv = x; bi = j; }
        }
        rv[t] = bv; ri[t] = bi;
        __syncthreads();
        for (int s = 128; s > 0; s >>= 1) {
            if (t < s) {
                float ov = rv[t + s]; int oi = ri[t + s];
                if (ov > rv[t] || (ov == rv[t] && oi < ri[t])) { rv[t] = ov; ri[t] = oi; }
            }
            __syncthreads();
        }
        if (t == 0) { topv[r] = rv[0]; topi[r] = ri[0]; arow[ri[0]] = -1.f; }
        __syncthreads();
    }
    if (t == 0) {
        float s = 1.f;
        for (int r = 0; r < 10; r++) s += topv[r];
        float inv = 1.f / s;
        for (int r = 0; r < 10; r++) {
            aN_idx[v * 11 + r] = topi[r];
            aN_val[v * 11 + r] = topv[r] * inv;
            row_idx[v * 10 + r] = topi[r];
            row_val[v * 10 + r] = topv[r];
            atomicAdd(&col_cnt[topi[r]], 1);
            atomicAdd(&col_sum[topi[r]], topv[r]);
        }
        aN_idx[v * 11 + 10] = v;
        aN_val[v * 11 + 10] = inv;
    }
}

__global__ __launch_bounds__(1024) void k_scan(const int* cnt, int* off,
                                               const float* csum, float* inv) {
    __shared__ int tmp[1024];
    int t = threadIdx.x;
    tmp[t] = cnt[t];
    __syncthreads();
    for (int s = 1; s < 1024; s <<= 1) {
        int v = 0;
        if (t >= s) v = tmp[t - s];
        __syncthreads();
        tmp[t] += v;
        __syncthreads();
    }
    off[t + 1] = tmp[t];
    if (t == 0) off[0] = 0;
    inv[t] = 1.0f / (csum[t] + 1.0f);
}

__global__ void k_scatter(const int* row_idx, const float* row_val, const int* off,
                          int* fill, int* aT_idx, float* aT_val) {
    int e = blockIdx.x * 256 + threadIdx.x;
    if (e >= 10240) return;
    int v = e / 10;
    int j = row_idx[e];
    int pos = off[j] + atomicAdd(&fill[j], 1);
    aT_idx[pos] = v;
    aT_val[pos] = row_val[e];
}

// ---------------- per-chunk kernels (hist/out pointers pre-offset by chunk) ----

// gate MLP + embed: writes gated (x1|x2) and hd_emb; grid = CB*3072
__global__ __launch_bounds__(256) void k_gate(const float* hist, const float* nodeu,
        const float* tide, const float* diwe,
        const float* Wg1, const float* bg1, const float* Wg2, const float* bg2,
        const float* Wemb, const float* bemb, float* gated, float* hd_emb) {
    __shared__ float w1[4096], w2[4096];
    __shared__ float gin[4][64], hid[4][64];
    __shared__ float sb1[64], sb2[64], we[128], be[64];
    int t = threadIdx.x;
    for (int i = t; i < 4096; i += 256) { w1[i] = Wg1[i]; w2[i] = Wg2[i]; }
    if (t < 64) { sb1[t] = bg1[t]; sb2[t] = bg2[t]; be[t] = bemb[t]; }
    if (t < 128) we[t] = Wemb[t];
    int r = t >> 6, lane = t & 63;
    int row = blockIdx.x * 4 + r;
    int n = row & 1023;
    const float* hrow = hist + (size_t)row * 4;
    float f0 = hrow[0], f1 = hrow[1];
    int tid_i = (int)(hrow[2] * 288.0f);
    int diw_i = (int)hrow[3];
    float g;
    if (lane < 40) g = nodeu[n * 40 + lane];
    else if (lane < 52) g = tide[tid_i * 12 + lane - 40];
    else g = diwe[diw_i * 12 + lane - 52];
    gin[r][lane] = g;
    __syncthreads();
    float acc = sb1[lane];
    for (int k = 0; k < 64; k++) acc += gin[r][k] * w1[k * 64 + lane];
    hid[r][lane] = acc > 0.f ? acc : 0.f;
    __syncthreads();
    acc = sb2[lane];
    for (int k = 0; k < 64; k++) acc += hid[r][k] * w2[k * 64 + lane];
    float gate = 1.f / (1.f + expf(-acc));
    float hd = f0 * we[lane] + f1 * we[64 + lane] + be[lane];
    float x1 = gate * hd;
    gated[(size_t)row * 128 + lane] = x1;
    gated[(size_t)row * 128 + 64 + lane] = hd - x1;
    hd_emb[(size_t)row * 64 + lane] = hd;
}

// xs[b,o,n,h] = relu(sum_t gated[b,t,n,xoff+h]*Wsc[o,t] + bsc[o]); grid = CB*256
__global__ __launch_bounds__(256) void k_wsc(const float* gated, const float* Wsc,
                                             const float* bsc, float* xs, int xoff) {
    __shared__ float w[384];
    __shared__ float sb[32];
    int t = threadIdx.x;
    if (t < 384) w[t] = Wsc[t];
    if (t < 32) sb[t] = bsc[t];
    __syncthreads();
    int idx = blockIdx.x * 256 + t;
    int h = idx & 63, n = (idx >> 6) & 1023, b = idx >> 16;
    float xv[12];
#pragma unroll
    for (int tt = 0; tt < 12; tt++)
        xv[tt] = gated[(size_t)((b * 12 + tt) * 1024 + n) * 128 + xoff + h];
#pragma unroll
    for (int o = 0; o < 32; o++) {
        float a = sb[o];
#pragma unroll
        for (int tt = 0; tt < 12; tt++) a += xv[tt] * w[o * 12 + tt];
        xs[(size_t)((b * 32 + o) * 1024 + n) * 64 + h] = a > 0.f ? a : 0.f;
    }
}

// out = 0.05*x + 0.95 * (A_norm @ hin); grid = CB*8192
__global__ __launch_bounds__(256) void k_spmm(float* out, const float* x, const float* hin,
        const int* aN_idx, const float* aN_val,
        const int* aT_idx, const float* aT_val,
        const int* off, const float* inv_cs, int mode) {
    int t = threadIdx.x, l = t & 63, sub = t >> 6;
    int g = blockIdx.x * 4 + sub;       // (bc, v)
    int v = g & 1023, bc = g >> 10;
    const float* base = hin + (size_t)bc * 65536;
    float s;
    if (mode == 0) {
        s = 0.f;
        for (int e = 0; e < 11; e++) {
            int w = aN_idx[v * 11 + e];
            s += aN_val[v * 11 + e] * base[w * 64 + l];
        }
    } else {
        s = base[v * 64 + l];
        int e0 = off[v], e1 = off[v + 1];
        for (int e = e0; e < e1; e++) s += aT_val[e] * base[aT_idx[e] * 64 + l];
        s *= inv_cs[v];
    }
    size_t oi = (size_t)g * 64 + l;
    out[oi] = 0.05f * x[oi] + 0.95f * s;
}

// mix projection: per (b,n) 64x64 tile (rows=(i,o), cols=l), K=96; grid = CB*1024
__global__ __launch_bounds__(256) void k_proj(const float* xs, const float* h1, const float* h2,
        const float* mw, const float* m1b, const float* m2b,
        float* mix, int xp, int cp) {
    __shared__ float Wl[96 * 64];
    __shared__ float Bt[96 * 64];
    int t = threadIdx.x;
    int b = blockIdx.x >> 10, n = blockIdx.x & 1023;
    for (int i = t; i < 6144; i += 256) {
        int k = i >> 6, col = i & 63;
        Wl[i] = mw[col * 96 + k];                     // mw flat (2,32,96), col=i2*32+o
    }
    for (int i = t; i < 6144; i += 256) {
        int k = i >> 6, l = i & 63;
        int q = k >> 5, c = k & 31;
        const float* Hq = (q == 0) ? xs : (q == 1 ? h1 : h2);
        Bt[i] = Hq[(size_t)((b * 32 + c) * 1024 + n) * 64 + l];
    }
    __syncthreads();
    int tx = t & 15, ty = t >> 4;
    int o0 = tx * 4, l0 = ty * 4;
    float acc[4][4];
#pragma unroll
    for (int io = 0; io < 4; io++) {
        float bias = 0.f;
        if (cp == 0) { int rrow = o0 + io; bias = m1b[rrow] + m2b[rrow]; }
#pragma unroll
        for (int il = 0; il < 4; il++) acc[io][il] = bias;
    }
    for (int k = 0; k < 96; k++) {
        float4 a = *(const float4*)&Wl[k * 64 + o0];
        float4 bb = *(const float4*)&Bt[k * 64 + l0];
        acc[0][0] += a.x * bb.x; acc[0][1] += a.x * bb.y; acc[0][2] += a.x * bb.z; acc[0][3] += a.x * bb.w;
        acc[1][0] += a.y * bb.x; acc[1][1] += a.y * bb.y; acc[1][2] += a.y * bb.z; acc[1][3] += a.y * bb.w;
        acc[2][0] += a.z * bb.x; acc[2][1] += a.z * bb.y; acc[2][2] += a.z * bb.z; acc[2][3] += a.z * bb.w;
        acc[3][0] += a.w * bb.x; acc[3][1] += a.w * bb.y; acc[3][2] += a.w * bb.z; acc[3][3] += a.w * bb.w;
    }
#pragma unroll
    for (int io = 0; io < 4; io++) {
        int rrow = o0 + io;
        int i2 = rrow >> 5, o = rrow & 31;
        float* gp = &mix[(size_t)((b * 32 + o) * 1024 + n) * 256 + (i2 * 2 + xp) * 64 + l0];
        if (cp == 0) {
#pragma unroll
            for (int il = 0; il < 4; il++) gp[il] = acc[io][il];
        } else {
#pragma unroll
            for (int il = 0; il < 4; il++) gp[il] += acc[io][il];
        }
    }
}

// fused Wtf1(relu)Wtf2, IN-PLACE on mix: 32 rows/block; grid = CB*1024
__global__ __launch_bounds__(256) void k_tf(float* mix, const float* W1, const float* B1,
                                            const float* W2, const float* B2) {
    __shared__ float A[32][256];
    __shared__ float Hd[32][256];
    int t = threadIdx.x;
    size_t row0 = (size_t)blockIdx.x * 32;
    for (int i = t; i < 8192; i += 256) A[i >> 8][i & 255] = mix[row0 * 256 + i];
    __syncthreads();
    int cg = t & 63, rg = t >> 6;
    int c0 = cg * 4, r0 = rg * 8;
    float acc[8][4];
    {
        float4 bb = *(const float4*)&B1[c0];
#pragma unroll
        for (int ri = 0; ri < 8; ri++) { acc[ri][0] = bb.x; acc[ri][1] = bb.y; acc[ri][2] = bb.z; acc[ri][3] = bb.w; }
    }
    for (int k = 0; k < 256; k += 4) {
        float4 w0 = *(const float4*)&W1[(k + 0) * 256 + c0];
        float4 w1 = *(const float4*)&W1[(k + 1) * 256 + c0];
        float4 w2 = *(const float4*)&W1[(k + 2) * 256 + c0];
        float4 w3 = *(const float4*)&W1[(k + 3) * 256 + c0];
#pragma unroll
        for (int ri = 0; ri < 8; ri++) {
            float4 a = *(const float4*)&A[r0 + ri][k];
            acc[ri][0] += a.x * w0.x + a.y * w1.x + a.z * w2.x + a.w * w3.x;
            acc[ri][1] += a.x * w0.y + a.y * w1.y + a.z * w2.y + a.w * w3.y;
            acc[ri][2] += a.x * w0.z + a.y * w1.z + a.z * w2.z + a.w * w3.z;
            acc[ri][3] += a.x * w0.w + a.y * w1.w + a.z * w2.w + a.w * w3.w;
        }
    }
#pragma unroll
    for (int ri = 0; ri < 8; ri++) {
        float4 h;
        h.x = fmaxf(acc[ri][0], 0.f); h.y = fmaxf(acc[ri][1], 0.f);
        h.z = fmaxf(acc[ri][2], 0.f); h.w = fmaxf(acc[ri][3], 0.f);
        *(float4*)&Hd[r0 + ri][c0] = h;
    }
    __syncthreads();
    {
        float4 bb = *(const float4*)&B2[c0];
#pragma unroll
        for (int ri = 0; ri < 8; ri++) { acc[ri][0] = bb.x; acc[ri][1] = bb.y; acc[ri][2] = bb.z; acc[ri][3] = bb.w; }
    }
    for (int k = 0; k < 256; k += 4) {
        float4 w0 = *(const float4*)&W2[(k + 0) * 256 + c0];
        float4 w1 = *(const float4*)&W2[(k + 1) * 256 + c0];
        float4 w2 = *(const float4*)&W2[(k + 2) * 256 + c0];
        float4 w3 = *(const float4*)&W2[(k + 3) * 256 + c0];
#pragma unroll
        for (int ri = 0; ri < 8; ri++) {
            float4 a = *(const float4*)&Hd[r0 + ri][k];
            acc[ri][0] += a.x * w0.x + a.y * w1.x + a.z * w2.x + a.w * w3.x;
            acc[ri][1] += a.x * w0.y + a.y * w1.y + a.z * w2.y + a.w * w3.y;
            acc[ri][2] += a.x * w0.z + a.y * w1.z + a.z * w2.z + a.w * w3.z;
            acc[ri][3] += a.x * w0.w + a.y * w1.w + a.z * w2.w + a.w * w3.w;
        }
    }
#pragma unroll
    for (int ri = 0; ri < 8; ri++) {
        float4 o;
        o.x = acc[ri][0]; o.y = acc[ri][1]; o.z = acc[ri][2]; o.w = acc[ri][3];
        *(float4*)&mix[(row0 + r0 + ri) * 256 + c0] = o;
    }
}

// fused ec1(relu)+ec2: block per (b,n), thread = l (256); grid = CB*1024
__global__ __launch_bounds__(256) void k_ec(const float* tfo, const float* W1, const float* B1,
                                            const float* W2, const float* B2, float* eco) {
    __shared__ float X[32][256];
    __shared__ float w1[128 * 32];
    __shared__ float w2[12 * 128];
    __shared__ float sb1[128], sb2[12];
    int t = threadIdx.x;
    int b = blockIdx.x >> 10, n = blockIdx.x & 1023;
    for (int i = t; i < 4096; i += 256) w1[i] = W1[i];
    for (int i = t; i < 1536; i += 256) w2[i] = W2[i];
    if (t < 128) sb1[t] = B1[t];
    if (t < 12) sb2[t] = B2[t];
    for (int i = t; i < 8192; i += 256) {
        int c = i >> 8, l = i & 255;
        X[c][l] = tfo[(size_t)((b * 32 + c) * 1024 + n) * 256 + l];
    }
    __syncthreads();
    float x[32];
#pragma unroll
    for (int c = 0; c < 32; c++) x[c] = X[c][t];
    float out[12];
#pragma unroll
    for (int p = 0; p < 12; p++) out[p] = sb2[p];
    for (int oc = 0; oc < 4; oc++) {
        float h[32];
#pragma unroll
        for (int oi = 0; oi < 32; oi++) {
            int o = oc * 32 + oi;
            float a = sb1[o];
            const float* wr = &w1[o * 32];
#pragma unroll
            for (int c = 0; c < 32; c += 4) {
                float4 w4 = *(const float4*)&wr[c];
                a += w4.x * x[c] + w4.y * x[c + 1] + w4.z * x[c + 2] + w4.w * x[c + 3];
            }
            h[oi] = a > 0.f ? a : 0.f;
        }
#pragma unroll
        for (int oi = 0; oi < 32; oi++) {
            int o = oc * 32 + oi;
            float hv = h[oi];
#pragma unroll
            for (int p = 0; p < 12; p++) out[p] += w2[p * 128 + o] * hv;
        }
    }
#pragma unroll
    for (int p = 0; p < 12; p++)
        eco[(size_t)((b * 12 + p) * 1024 + n) * 256 + t] = out[p];
}

// fused fc1(relu)+fc2: 8 rows/block; grid = CB*1536
__global__ __launch_bounds__(256) void k_fc(const float* gated, const float* eco,
        const float* hd_emb, const float* hist, const float* tide, const float* diwe,
        const float* W1, const float* B1, const float* W2, const float* B2, float* fbuf) {
    __shared__ float A[8][472];
    __shared__ float Hd[8][512];
    __shared__ float red[8][96];
    __shared__ float w2l[1536];
    int t = threadIdx.x;
    int row0 = blockIdx.x * 8;
    for (int i = t; i < 1536; i += 256) w2l[i] = W2[i];
    for (int r = 0; r < 8; r++) {
        int row = row0 + r;
        int n = row & 1023, bt = row >> 10;
        int b = bt / 12, tt = bt - b * 12;
        const float* hrow = &hist[(size_t)row * 4];
        int tid_i = (int)(hrow[2] * 288.0f);
        int diw_i = (int)hrow[3];
        for (int j = t; j < 472; j += 256) {
            float v;
            if (j < 128) v = gated[(size_t)row * 128 + j];
            else if (j < 384) v = eco[(size_t)((b * 12 + tt) * 1024 + n) * 256 + (j - 128)];
            else if (j < 396) v = tide[tid_i * 12 + j - 384];
            else if (j < 408) v = diwe[diw_i * 12 + j - 396];
            else v = hd_emb[(size_t)row * 64 + j - 408];
            A[r][j] = fmaxf(v, 0.f);
        }
    }
    __syncthreads();
    float acc0[8], acc1[8];
    float b1a = B1[t], b1b = B1[t + 256];
#pragma unroll
    for (int r = 0; r < 8; r++) { acc0[r] = b1a; acc1[r] = b1b; }
    for (int k = 0; k < 472; k += 4) {
        float wa[4], wb[4];
#pragma unroll
        for (int q = 0; q < 4; q++) {
            wa[q] = W1[(k + q) * 512 + t];
            wb[q] = W1[(k + q) * 512 + t + 256];
        }
#pragma unroll
        for (int r = 0; r < 8; r++) {
            float4 a = *(const float4*)&A[r][k];
            acc0[r] += a.x * wa[0] + a.y * wa[1] + a.z * wa[2] + a.w * wa[3];
            acc1[r] += a.x * wb[0] + a.y * wb[1] + a.z * wb[2] + a.w * wb[3];
        }
    }
#pragma unroll
    for (int r = 0; r < 8; r++) {
        Hd[r][t] = fmaxf(acc0[r], 0.f);
        Hd[r][t + 256] = fmaxf(acc1[r], 0.f);
    }
    __syncthreads();
    {
        int r = t >> 5, seg = t & 31;
        float p0 = 0.f, p1 = 0.f, p2 = 0.f;
        for (int k = seg * 16; k < seg * 16 + 16; k++) {
            float h = Hd[r][k];
            p0 += h * w2l[k * 3];
            p1 += h * w2l[k * 3 + 1];
            p2 += h * w2l[k * 3 + 2];
        }
        red[r][seg] = p0;
        red[r][32 + seg] = p1;
        red[r][64 + seg] = p2;
    }
    __syncthreads();
    if (t < 24) {
        int rr = t / 3, p = t - rr * 3;
        float s = B2[p];
        for (int seg = 0; seg < 32; seg++) s += red[rr][p * 32 + seg];
        fbuf[(size_t)(row0 + rr) * 3 + p] = s;
    }
}

// final conv1x1 over time + transpose; grid = CB*48; out pre-offset by chunk
__global__ void k_ec3(const float* f, const float* W, const float* bv, float* out) {
    int idx = blockIdx.x * 256 + threadIdx.x;
    int l = idx % 3;
    int rest = idx / 3;
    int o = rest & 3;
    int n = (rest >> 2) & 1023;
    int b = rest >> 12;
    float s = bv[o];
#pragma unroll
    for (int c = 0; c < 12; c++)
        s += f[(size_t)((b * 12 + c) * 1024 + n) * 3 + l] * W[o * 12 + c];
    out[idx] = s;
}

// ---------------- launcher ----------------
extern "C" void kernel_launch(void* const* d_in, const int* in_sizes, int n_in,
                              void* d_out, int out_size, void* d_ws, size_t ws_size,
                              hipStream_t stream) {
    const float* hist = (const float*)d_in[0];
    const float* node_emb_u = (const float*)d_in[1];
    const float* T_i_D_emb = (const float*)d_in[2];
    const float* D_i_W_emb = (const float*)d_in[3];
    const float* gc_emb1 = (const float*)d_in[4];
    const float* gc_emb2 = (const float*)d_in[5];
    const float* gc_w1 = (const float*)d_in[6];
    const float* gc_b1 = (const float*)d_in[7];
    const float* gc_w2 = (const float*)d_in[8];
    const float* gc_b2 = (const float*)d_in[9];
    const float* W_emb = (const float*)d_in[10];
    const float* b_emb = (const float*)d_in[11];
    const float* Wg1 = (const float*)d_in[12];
    const float* bg1 = (const float*)d_in[13];
    const float* Wg2 = (const float*)d_in[14];
    const float* bg2 = (const float*)d_in[15];
    const float* Wsc = (const float*)d_in[16];
    const float* bsc = (const float*)d_in[17];
    const float* mix1_w = (const float*)d_in[18];
    const float* mix1_b = (const float*)d_in[19];
    const float* mix2_w = (const float*)d_in[20];
    const float* mix2_b = (const float*)d_in[21];
    const float* Wtf1 = (const float*)d_in[22];
    const float* btf1 = (const float*)d_in[23];
    const float* Wtf2 = (const float*)d_in[24];
    const float* btf2 = (const float*)d_in[25];
    const float* Wec1 = (const float*)d_in[26];
    const float* bec1 = (const float*)d_in[27];
    const float* Wec2 = (const float*)d_in[28];
    const float* bec2 = (const float*)d_in[29];
    const float* Wfc1 = (const float*)d_in[30];
    const float* bfc1 = (const float*)d_in[31];
    const float* Wfc2 = (const float*)d_in[32];
    const float* bfc2 = (const float*)d_in[33];
    const float* Wec3 = (const float*)d_in[34];
    const float* bec3 = (const float*)d_in[35];

    float* ws = (float*)d_ws;
    float* n1 = ws + F_N1;
    float* n2 = ws + F_N2;
    float* aN_val = ws + F_ANVAL;
    float* row_val = ws + F_ROWVAL;
    float* col_sum = ws + F_COLSUM;
    float* inv_cs = ws + F_INVCS;
    float* aT_val = ws + F_ATVAL;
    int* aN_idx = (int*)(ws + I_ANIDX);
    int* row_idx = (int*)(ws + I_ROWIDX);
    int* col_cnt = (int*)(ws + I_COLCNT);
    int* col_off = (int*)(ws + I_COLOFF);
    int* col_fill = (int*)(ws + I_COLFILL);
    int* aT_idx = (int*)(ws + I_ATIDX);

    // pick largest batch-chunk CB that fits the workspace
    size_t avail = ws_size / 4;   // floats
    int CB = 8;
    while (CB > 1 && GRAPH_FLOATS + (size_t)CB * PB_TOTAL > avail) CB >>= 1;
    int nchunk = 8 / CB;

    float* gated = ws + GRAPH_FLOATS;
    float* hd_emb = gated + (size_t)CB * PB_GATED;
    float* xs = hd_emb + (size_t)CB * PB_HD;
    float* h1 = xs + (size_t)CB * PB_XS;
    float* h2 = h1 + (size_t)CB * PB_XS;
    float* mix = h2 + (size_t)CB * PB_XS;
    float* eco = xs;    // alias: xs+h1 region (CB*4M floats) >= eco (CB*3M floats)
    float* fbuf = h2;   // alias: h2 dead by k_fc

    // ---- graph construction (once) ----
    k_init<<<4, 256, 0, stream>>>(col_cnt, col_fill, col_sum);
    k_embed<<<320, 256, 0, stream>>>(gc_emb1, gc_emb2, gc_w1, gc_b1, gc_w2, gc_b2, n1, n2);
    k_adj<<<1024, 256, 0, stream>>>(n1, n2, aN_val, aN_idx, row_val, row_idx, col_cnt, col_sum);
    k_scan<<<1, 1024, 0, stream>>>(col_cnt, col_off, col_sum, inv_cs);
    k_scatter<<<40, 256, 0, stream>>>(row_idx, row_val, col_off, col_fill, aT_idx, aT_val);

    // ---- per-chunk pipeline ----
    for (int ch = 0; ch < nchunk; ch++) {
        const float* hist_c = hist + (size_t)ch * CB * ROWS_PER_B * 4;
        float* out_c = (float*)d_out + (size_t)ch * CB * ROWS_PER_B;  // 12288 out/batch

        k_gate<<<CB * 3072, 256, 0, stream>>>(hist_c, node_emb_u, T_i_D_emb, D_i_W_emb,
                                              Wg1, bg1, Wg2, bg2, W_emb, b_emb, gated, hd_emb);
        for (int xp = 0; xp < 2; xp++) {
            k_wsc<<<CB * 256, 256, 0, stream>>>(gated, Wsc, bsc, xs, xp * 64);
            for (int cp = 0; cp < 2; cp++) {
                k_spmm<<<CB * 8192, 256, 0, stream>>>(h1, xs, xs, aN_idx, aN_val, aT_idx, aT_val,
                                                      col_off, inv_cs, cp);
                k_spmm<<<CB * 8192, 256, 0, stream>>>(h2, xs, h1, aN_idx, aN_val, aT_idx, aT_val,
                                                      col_off, inv_cs, cp);
                k_proj<<<CB * 1024, 256, 0, stream>>>(xs, h1, h2, cp ? mix2_w : mix1_w,
                                                      mix1_b, mix2_b, mix, xp, cp);
            }
        }
        k_tf<<<CB * 1024, 256, 0, stream>>>(mix, Wtf1, btf1, Wtf2, btf2);
        k_ec<<<CB * 1024, 256, 0, stream>>>(mix, Wec1, bec1, Wec2, bec2, eco);
        k_fc<<<CB * 1536, 256, 0, stream>>>(gated, eco, hd_emb, hist_c, T_i_D_emb, D_i_W_emb,
                                            Wfc1, bfc1, Wfc2, bfc2, fbuf);
        k_ec3<<<CB * 48, 256, 0, stream>>>(fbuf, Wec3, bec3, out_c);
    }
}

// Round 3
// 4719.259 us; speedup vs baseline: 1.3495x; 1.3495x over previous
//
#include <hip/hip_runtime.h>
#include <math.h>

// ---------------- constants ----------------
constexpr int ROWS_PER_B = 12 * 1024;    // rows (b,t,n) per batch element

// ---------------- graph workspace (float offsets, < 524288) ----------------
constexpr size_t F_N1 = 0;              // 1024*40
constexpr size_t F_N2 = 40960;
constexpr size_t F_ANVAL = 81920;       // 1024*11
constexpr size_t F_ROWVAL = 93184;      // 1024*10
constexpr size_t F_COLSUM = 103424;     // 1024
constexpr size_t F_INVCS = 104448;      // 1024
constexpr size_t F_ATVAL = 105472;      // 10240
constexpr size_t I_ANIDX = 115712;      // ints stored in float slots
constexpr size_t I_ROWIDX = 126976;
constexpr size_t I_COLCNT = 137216;
constexpr size_t I_COLOFF = 138240;     // 1025
constexpr size_t I_COLFILL = 139265;
constexpr size_t I_ATIDX = 140289;      // ends 150529 < 524288
constexpr size_t GRAPH_FLOATS = 524288;

// per-chunk float counts (per batch element)
constexpr size_t PB_GATED = (size_t)ROWS_PER_B * 128;   // 1572864
constexpr size_t PB_HD = (size_t)ROWS_PER_B * 64;       // 786432
constexpr size_t PB_XS = (size_t)32 * 1024 * 64;        // 2097152
constexpr size_t PB_MIX = (size_t)32 * 1024 * 256;      // 8388608
constexpr size_t PB_TOTAL = PB_GATED + PB_HD + 3 * PB_XS + PB_MIX; // 17039360

// ---------------- graph kernels ----------------

__global__ void k_init(int* cnt, int* fill, float* csum) {
    int t = blockIdx.x * 256 + threadIdx.x;
    if (t < 1024) { cnt[t] = 0; fill[t] = 0; csum[t] = 0.f; }
}

__global__ void k_embed(const float* e1, const float* e2, const float* w1, const float* b1,
                        const float* w2, const float* b2, float* n1, float* n2) {
    int idx = blockIdx.x * 256 + threadIdx.x;   // < 81920
    if (idx >= 81920) return;
    int m = idx / 40960, rem = idx - m * 40960;
    int i = rem / 40, j = rem - i * 40;
    const float* e = m ? e2 : e1;
    const float* w = m ? w2 : w1;
    const float* bv = m ? b2 : b1;
    float a = bv[j];
    for (int k = 0; k < 40; k++) a += e[i * 40 + k] * w[k * 40 + j];
    (m ? n2 : n1)[i * 40 + j] = tanhf(3.0f * a);
}

__global__ __launch_bounds__(256) void k_adj(const float* n1, const float* n2,
        float* aN_val, int* aN_idx, float* row_val, int* row_idx,
        int* col_cnt, float* col_sum) {
    __shared__ float arow[1024];
    __shared__ float n1v[40], n2v[40];
    __shared__ float rv[256];
    __shared__ int ri[256];
    __shared__ float topv[10];
    __shared__ int topi[10];
    int v = blockIdx.x, t = threadIdx.x;
    if (t < 40) { n1v[t] = n1[v * 40 + t]; n2v[t] = n2[v * 40 + t]; }
    __syncthreads();
    for (int j = t; j < 1024; j += 256) {
        float d1 = 0.f, d2 = 0.f;
        for (int k = 0; k < 40; k++) {
            d1 += n1v[k] * n2[j * 40 + k];
            d2 += n2v[k] * n1[j * 40 + k];
        }
        float a = tanhf(3.0f * (d1 - d2));
        arow[j] = a > 0.f ? a : 0.f;
    }
    __syncthreads();
    for (int r = 0; r < 10; r++) {
        float bv = -1.f; int bi = 1 << 30;
        for (int j = t; j < 1024; j += 256) {
            float x = arow[j];
            if (x > bv || (x == bv && j < bi)) { bv = x; bi = j; }
        }
        rv[t] = bv; ri[t] = bi;
        __syncthreads();
        for (int s = 128; s > 0; s >>= 1) {
            if (t < s) {
                float ov = rv[t + s]; int oi = ri[t + s];
                if (ov > rv[t] || (ov == rv[t] && oi < ri[t])) { rv[t] = ov; ri[t] = oi; }
            }
            __syncthreads();
        }
        if (t == 0) { topv[r] = rv[0]; topi[r] = ri[0]; arow[ri[0]] = -1.f; }
        __syncthreads();
    }
    if (t == 0) {
        float s = 1.f;
        for (int r = 0; r < 10; r++) s += topv[r];
        float inv = 1.f / s;
        for (int r = 0; r < 10; r++) {
            aN_idx[v * 11 + r] = topi[r];
            aN_val[v * 11 + r] = topv[r] * inv;
            row_idx[v * 10 + r] = topi[r];
            row_val[v * 10 + r] = topv[r];
            atomicAdd(&col_cnt[topi[r]], 1);
            atomicAdd(&col_sum[topi[r]], topv[r]);
        }
        aN_idx[v * 11 + 10] = v;
        aN_val[v * 11 + 10] = inv;
    }
}

__global__ __launch_bounds__(1024) void k_scan(const int* cnt, int* off,
                                               const float* csum, float* inv) {
    __shared__ int tmp[1024];
    int t = threadIdx.x;
    tmp[t] = cnt[t];
    __syncthreads();
    for (int s = 1; s < 1024; s <<= 1) {
        int v = 0;
        if (t >= s) v = tmp[t - s];
        __syncthreads();
        tmp[t] += v;
        __syncthreads();
    }
    off[t + 1] = tmp[t];
    if (t == 0) off[0] = 0;
    inv[t] = 1.0f / (csum[t] + 1.0f);
}

__global__ void k_scatter(const int* row_idx, const float* row_val, const int* off,
                          int* fill, int* aT_idx, float* aT_val) {
    int e = blockIdx.x * 256 + threadIdx.x;
    if (e >= 10240) return;
    int v = e / 10;
    int j = row_idx[e];
    int pos = off[j] + atomicAdd(&fill[j], 1);
    aT_idx[pos] = v;
    aT_val[pos] = row_val[e];
}

// ---------------- per-chunk kernels ----------------

// gate MLP + embed; grid = CB*3072
__global__ __launch_bounds__(256) void k_gate(const float* hist, const float* nodeu,
        const float* tide, const float* diwe,
        const float* Wg1, const float* bg1, const float* Wg2, const float* bg2,
        const float* Wemb, const float* bemb, float* gated, float* hd_emb) {
    __shared__ float w1[4096], w2[4096];
    __shared__ float gin[4][64], hid[4][64];
    __shared__ float sb1[64], sb2[64], we[128], be[64];
    int t = threadIdx.x;
    for (int i = t; i < 4096; i += 256) { w1[i] = Wg1[i]; w2[i] = Wg2[i]; }
    if (t < 64) { sb1[t] = bg1[t]; sb2[t] = bg2[t]; be[t] = bemb[t]; }
    if (t < 128) we[t] = Wemb[t];
    int r = t >> 6, lane = t & 63;
    int row = blockIdx.x * 4 + r;
    int n = row & 1023;
    const float* hrow = hist + (size_t)row * 4;
    float f0 = hrow[0], f1 = hrow[1];
    int tid_i = (int)(hrow[2] * 288.0f);
    int diw_i = (int)hrow[3];
    float g;
    if (lane < 40) g = nodeu[n * 40 + lane];
    else if (lane < 52) g = tide[tid_i * 12 + lane - 40];
    else g = diwe[diw_i * 12 + lane - 52];
    gin[r][lane] = g;
    __syncthreads();
    float acc = sb1[lane];
    for (int k = 0; k < 64; k++) acc += gin[r][k] * w1[k * 64 + lane];
    hid[r][lane] = acc > 0.f ? acc : 0.f;
    __syncthreads();
    acc = sb2[lane];
    for (int k = 0; k < 64; k++) acc += hid[r][k] * w2[k * 64 + lane];
    float gate = 1.f / (1.f + expf(-acc));
    float hd = f0 * we[lane] + f1 * we[64 + lane] + be[lane];
    float x1 = gate * hd;
    gated[(size_t)row * 128 + lane] = x1;
    gated[(size_t)row * 128 + 64 + lane] = hd - x1;
    hd_emb[(size_t)row * 64 + lane] = hd;
}

// xs[b,o,n,h] = relu(sum_t gated*Wsc + bsc); grid = CB*256
__global__ __launch_bounds__(256) void k_wsc(const float* gated, const float* Wsc,
                                             const float* bsc, float* xs, int xoff) {
    __shared__ float w[384];
    __shared__ float sb[32];
    int t = threadIdx.x;
    if (t < 384) w[t] = Wsc[t];
    if (t < 32) sb[t] = bsc[t];
    __syncthreads();
    int idx = blockIdx.x * 256 + t;
    int h = idx & 63, n = (idx >> 6) & 1023, b = idx >> 16;
    float xv[12];
#pragma unroll
    for (int tt = 0; tt < 12; tt++)
        xv[tt] = gated[(size_t)((b * 12 + tt) * 1024 + n) * 128 + xoff + h];
#pragma unroll
    for (int o = 0; o < 32; o++) {
        float a = sb[o];
#pragma unroll
        for (int tt = 0; tt < 12; tt++) a += xv[tt] * w[o * 12 + tt];
        xs[(size_t)((b * 32 + o) * 1024 + n) * 64 + h] = a > 0.f ? a : 0.f;
    }
}

// out = 0.05*x + 0.95*(A_norm @ hin), float4 lanes; grid = CB*2048 (16 rows/block)
__global__ __launch_bounds__(256) void k_spmm(float* out, const float* x, const float* hin,
        const int* aN_idx, const float* aN_val,
        const int* aT_idx, const float* aT_val,
        const int* off, const float* inv_cs, int mode) {
    int t = threadIdx.x;
    int l4 = t & 15, r = t >> 4;            // 16 rows x 16 float4-lanes
    int g = blockIdx.x * 16 + r;            // row id (bc, v)
    int v = g & 1023, bc = g >> 10;
    const float4* base = (const float4*)hin + (size_t)bc * 16384;
    float4 s;
    if (mode == 0) {
        s.x = s.y = s.z = s.w = 0.f;
#pragma unroll
        for (int e = 0; e < 11; e++) {
            int w = aN_idx[v * 11 + e];
            float a = aN_val[v * 11 + e];
            float4 hv = base[w * 16 + l4];
            s.x += a * hv.x; s.y += a * hv.y; s.z += a * hv.z; s.w += a * hv.w;
        }
    } else {
        s = base[v * 16 + l4];
        int e0 = off[v], e1 = off[v + 1];
        for (int e = e0; e < e1; e++) {
            int w = aT_idx[e];
            float a = aT_val[e];
            float4 hv = base[w * 16 + l4];
            s.x += a * hv.x; s.y += a * hv.y; s.z += a * hv.z; s.w += a * hv.w;
        }
        float ic = inv_cs[v];
        s.x *= ic; s.y *= ic; s.z *= ic; s.w *= ic;
    }
    size_t oi = (size_t)g * 16 + l4;
    float4 xv = ((const float4*)x)[oi];
    float4 o;
    o.x = 0.05f * xv.x + 0.95f * s.x;
    o.y = 0.05f * xv.y + 0.95f * s.y;
    o.z = 0.05f * xv.z + 0.95f * s.z;
    o.w = 0.05f * xv.w + 0.95f * s.w;
    ((float4*)out)[oi] = o;
}

// mix projection; grid = CB*1024
__global__ __launch_bounds__(256) void k_proj(const float* xs, const float* h1, const float* h2,
        const float* mw, const float* m1b, const float* m2b,
        float* mix, int xp, int cp) {
    __shared__ float Wl[96 * 64];
    __shared__ float Bt[96 * 64];
    int t = threadIdx.x;
    int b = blockIdx.x >> 10, n = blockIdx.x & 1023;
    for (int i = t; i < 6144; i += 256) {
        int k = i >> 6, col = i & 63;
        Wl[i] = mw[col * 96 + k];
    }
    for (int i = t; i < 6144; i += 256) {
        int k = i >> 6, l = i & 63;
        int q = k >> 5, c = k & 31;
        const float* Hq = (q == 0) ? xs : (q == 1 ? h1 : h2);
        Bt[i] = Hq[(size_t)((b * 32 + c) * 1024 + n) * 64 + l];
    }
    __syncthreads();
    int tx = t & 15, ty = t >> 4;
    int o0 = tx * 4, l0 = ty * 4;
    float acc[4][4];
#pragma unroll
    for (int io = 0; io < 4; io++) {
        float bias = 0.f;
        if (cp == 0) { int rrow = o0 + io; bias = m1b[rrow] + m2b[rrow]; }
#pragma unroll
        for (int il = 0; il < 4; il++) acc[io][il] = bias;
    }
    for (int k = 0; k < 96; k++) {
        float4 a = *(const float4*)&Wl[k * 64 + o0];
        float4 bb = *(const float4*)&Bt[k * 64 + l0];
        acc[0][0] += a.x * bb.x; acc[0][1] += a.x * bb.y; acc[0][2] += a.x * bb.z; acc[0][3] += a.x * bb.w;
        acc[1][0] += a.y * bb.x; acc[1][1] += a.y * bb.y; acc[1][2] += a.y * bb.z; acc[1][3] += a.y * bb.w;
        acc[2][0] += a.z * bb.x; acc[2][1] += a.z * bb.y; acc[2][2] += a.z * bb.z; acc[2][3] += a.z * bb.w;
        acc[3][0] += a.w * bb.x; acc[3][1] += a.w * bb.y; acc[3][2] += a.w * bb.z; acc[3][3] += a.w * bb.w;
    }
#pragma unroll
    for (int io = 0; io < 4; io++) {
        int rrow = o0 + io;
        int i2 = rrow >> 5, o = rrow & 31;
        float* gp = &mix[(size_t)((b * 32 + o) * 1024 + n) * 256 + (i2 * 2 + xp) * 64 + l0];
        if (cp == 0) {
#pragma unroll
            for (int il = 0; il < 4; il++) gp[il] = acc[io][il];
        } else {
#pragma unroll
            for (int il = 0; il < 4; il++) gp[il] += acc[io][il];
        }
    }
}

// fused Wtf1(relu)Wtf2 in-place on mix; grid = CB*1024
__global__ __launch_bounds__(256) void k_tf(float* mix, const float* W1, const float* B1,
                                            const float* W2, const float* B2) {
    __shared__ float A[32][256];
    __shared__ float Hd[32][256];
    int t = threadIdx.x;
    size_t row0 = (size_t)blockIdx.x * 32;
    for (int i = t; i < 8192; i += 256) A[i >> 8][i & 255] = mix[row0 * 256 + i];
    __syncthreads();
    int cg = t & 63, rg = t >> 6;
    int c0 = cg * 4, r0 = rg * 8;
    float acc[8][4];
    {
        float4 bb = *(const float4*)&B1[c0];
#pragma unroll
        for (int ri = 0; ri < 8; ri++) { acc[ri][0] = bb.x; acc[ri][1] = bb.y; acc[ri][2] = bb.z; acc[ri][3] = bb.w; }
    }
    for (int k = 0; k < 256; k += 4) {
        float4 w0 = *(const float4*)&W1[(k + 0) * 256 + c0];
        float4 w1 = *(const float4*)&W1[(k + 1) * 256 + c0];
        float4 w2 = *(const float4*)&W1[(k + 2) * 256 + c0];
        float4 w3 = *(const float4*)&W1[(k + 3) * 256 + c0];
#pragma unroll
        for (int ri = 0; ri < 8; ri++) {
            float4 a = *(const float4*)&A[r0 + ri][k];
            acc[ri][0] += a.x * w0.x + a.y * w1.x + a.z * w2.x + a.w * w3.x;
            acc[ri][1] += a.x * w0.y + a.y * w1.y + a.z * w2.y + a.w * w3.y;
            acc[ri][2] += a.x * w0.z + a.y * w1.z + a.z * w2.z + a.w * w3.z;
            acc[ri][3] += a.x * w0.w + a.y * w1.w + a.z * w2.w + a.w * w3.w;
        }
    }
#pragma unroll
    for (int ri = 0; ri < 8; ri++) {
        float4 h;
        h.x = fmaxf(acc[ri][0], 0.f); h.y = fmaxf(acc[ri][1], 0.f);
        h.z = fmaxf(acc[ri][2], 0.f); h.w = fmaxf(acc[ri][3], 0.f);
        *(float4*)&Hd[r0 + ri][c0] = h;
    }
    __syncthreads();
    {
        float4 bb = *(const float4*)&B2[c0];
#pragma unroll
        for (int ri = 0; ri < 8; ri++) { acc[ri][0] = bb.x; acc[ri][1] = bb.y; acc[ri][2] = bb.z; acc[ri][3] = bb.w; }
    }
    for (int k = 0; k < 256; k += 4) {
        float4 w0 = *(const float4*)&W2[(k + 0) * 256 + c0];
        float4 w1 = *(const float4*)&W2[(k + 1) * 256 + c0];
        float4 w2 = *(const float4*)&W2[(k + 2) * 256 + c0];
        float4 w3 = *(const float4*)&W2[(k + 3) * 256 + c0];
#pragma unroll
        for (int ri = 0; ri < 8; ri++) {
            float4 a = *(const float4*)&Hd[r0 + ri][k];
            acc[ri][0] += a.x * w0.x + a.y * w1.x + a.z * w2.x + a.w * w3.x;
            acc[ri][1] += a.x * w0.y + a.y * w1.y + a.z * w2.y + a.w * w3.y;
            acc[ri][2] += a.x * w0.z + a.y * w1.z + a.z * w2.z + a.w * w3.z;
            acc[ri][3] += a.x * w0.w + a.y * w1.w + a.z * w2.w + a.w * w3.w;
        }
    }
#pragma unroll
    for (int ri = 0; ri < 8; ri++) {
        float4 o;
        o.x = acc[ri][0]; o.y = acc[ri][1]; o.z = acc[ri][2]; o.w = acc[ri][3];
        *(float4*)&mix[(row0 + r0 + ri) * 256 + c0] = o;
    }
}

// fused ec1(relu)+ec2: weights via wave-uniform (scalar) global reads; grid = CB*1024
__global__ __launch_bounds__(256) void k_ec(const float* tfo, const float* W1, const float* B1,
                                            const float* W2, const float* B2, float* eco) {
    __shared__ float X[32][256];
    int t = threadIdx.x;
    int b = blockIdx.x >> 10, n = blockIdx.x & 1023;
    for (int i = t; i < 8192; i += 256) {
        int c = i >> 8, l = i & 255;
        X[c][l] = tfo[(size_t)((b * 32 + c) * 1024 + n) * 256 + l];
    }
    __syncthreads();
    float x[32];
#pragma unroll
    for (int c = 0; c < 32; c++) x[c] = X[c][t];
    float out[12];
#pragma unroll
    for (int p = 0; p < 12; p++) out[p] = B2[p];      // uniform -> s_load
#pragma unroll 2
    for (int o = 0; o < 128; o++) {
        float a = B1[o];                               // uniform
        const float* wr = &W1[o * 32];                 // uniform base
#pragma unroll
        for (int c = 0; c < 32; c++) a += wr[c] * x[c];
        a = a > 0.f ? a : 0.f;
#pragma unroll
        for (int p = 0; p < 12; p++) out[p] += W2[p * 128 + o] * a;  // uniform
    }
#pragma unroll
    for (int p = 0; p < 12; p++)
        eco[(size_t)((b * 12 + p) * 1024 + n) * 256 + t] = out[p];
}

// fused fc1(relu)+fc2: 16 rows/block; red aliases A; grid = CB*768
__global__ __launch_bounds__(256) void k_fc(const float* gated, const float* eco,
        const float* hd_emb, const float* hist, const float* tide, const float* diwe,
        const float* W1, const float* B1, const float* W2, const float* B2, float* fbuf) {
    __shared__ float A[16][472];
    __shared__ float Hd[16][512];
    float* redp = (float*)A;   // reused after A is dead (post fc1 k-loop)
    int t = threadIdx.x;
    int row0 = blockIdx.x * 16;
    for (int r = 0; r < 16; r++) {
        int row = row0 + r;
        int n = row & 1023, bt = row >> 10;
        int b = bt / 12, tt = bt - b * 12;
        const float* hrow = &hist[(size_t)row * 4];
        int tid_i = (int)(hrow[2] * 288.0f);
        int diw_i = (int)hrow[3];
        for (int j = t; j < 472; j += 256) {
            float v;
            if (j < 128) v = gated[(size_t)row * 128 + j];
            else if (j < 384) v = eco[(size_t)((b * 12 + tt) * 1024 + n) * 256 + (j - 128)];
            else if (j < 396) v = tide[tid_i * 12 + j - 384];
            else if (j < 408) v = diwe[diw_i * 12 + j - 396];
            else v = hd_emb[(size_t)row * 64 + j - 408];
            A[r][j] = fmaxf(v, 0.f);
        }
    }
    __syncthreads();
    float acc0[16], acc1[16];
    float b1a = B1[t], b1b = B1[t + 256];
#pragma unroll
    for (int r = 0; r < 16; r++) { acc0[r] = b1a; acc1[r] = b1b; }
    for (int k = 0; k < 472; k += 4) {
        float wa[4], wb[4];
#pragma unroll
        for (int q = 0; q < 4; q++) {
            wa[q] = W1[(k + q) * 512 + t];
            wb[q] = W1[(k + q) * 512 + t + 256];
        }
#pragma unroll
        for (int r = 0; r < 16; r++) {
            float4 a = *(const float4*)&A[r][k];
            acc0[r] += a.x * wa[0] + a.y * wa[1] + a.z * wa[2] + a.w * wa[3];
            acc1[r] += a.x * wb[0] + a.y * wb[1] + a.z * wb[2] + a.w * wb[3];
        }
    }
    __syncthreads();   // all A reads done before redp overwrites A
#pragma unroll
    for (int r = 0; r < 16; r++) {
        Hd[r][t] = fmaxf(acc0[r], 0.f);
        Hd[r][t + 256] = fmaxf(acc1[r], 0.f);
    }
    __syncthreads();
    {
        int r = t >> 4, seg = t & 15;    // 16 rows x 16 segs
        float p0 = 0.f, p1 = 0.f, p2 = 0.f;
        for (int j = 0; j < 32; j++) {
            int k = seg + j * 16;        // stride-1 across lanes: no bank conflict
            float h = Hd[r][k];
            p0 += h * W2[k * 3];
            p1 += h * W2[k * 3 + 1];
            p2 += h * W2[k * 3 + 2];
        }
        redp[r * 48 + seg] = p0;
        redp[r * 48 + 16 + seg] = p1;
        redp[r * 48 + 32 + seg] = p2;
    }
    __syncthreads();
    if (t < 48) {
        int rr = t / 3, p = t - rr * 3;
        float s = B2[p];
        for (int seg = 0; seg < 16; seg++) s += redp[rr * 48 + p * 16 + seg];
        fbuf[(size_t)(row0 + rr) * 3 + p] = s;
    }
}

// final conv1x1 over time + transpose; grid = CB*48
__global__ void k_ec3(const float* f, const float* W, const float* bv, float* out) {
    int idx = blockIdx.x * 256 + threadIdx.x;
    int l = idx % 3;
    int rest = idx / 3;
    int o = rest & 3;
    int n = (rest >> 2) & 1023;
    int b = rest >> 12;
    float s = bv[o];
#pragma unroll
    for (int c = 0; c < 12; c++)
        s += f[(size_t)((b * 12 + c) * 1024 + n) * 3 + l] * W[o * 12 + c];
    out[idx] = s;
}

// ---------------- launcher ----------------
extern "C" void kernel_launch(void* const* d_in, const int* in_sizes, int n_in,
                              void* d_out, int out_size, void* d_ws, size_t ws_size,
                              hipStream_t stream) {
    const float* hist = (const float*)d_in[0];
    const float* node_emb_u = (const float*)d_in[1];
    const float* T_i_D_emb = (const float*)d_in[2];
    const float* D_i_W_emb = (const float*)d_in[3];
    const float* gc_emb1 = (const float*)d_in[4];
    const float* gc_emb2 = (const float*)d_in[5];
    const float* gc_w1 = (const float*)d_in[6];
    const float* gc_b1 = (const float*)d_in[7];
    const float* gc_w2 = (const float*)d_in[8];
    const float* gc_b2 = (const float*)d_in[9];
    const float* W_emb = (const float*)d_in[10];
    const float* b_emb = (const float*)d_in[11];
    const float* Wg1 = (const float*)d_in[12];
    const float* bg1 = (const float*)d_in[13];
    const float* Wg2 = (const float*)d_in[14];
    const float* bg2 = (const float*)d_in[15];
    const float* Wsc = (const float*)d_in[16];
    const float* bsc = (const float*)d_in[17];
    const float* mix1_w = (const float*)d_in[18];
    const float* mix1_b = (const float*)d_in[19];
    const float* mix2_w = (const float*)d_in[20];
    const float* mix2_b = (const float*)d_in[21];
    const float* Wtf1 = (const float*)d_in[22];
    const float* btf1 = (const float*)d_in[23];
    const float* Wtf2 = (const float*)d_in[24];
    const float* btf2 = (const float*)d_in[25];
    const float* Wec1 = (const float*)d_in[26];
    const float* bec1 = (const float*)d_in[27];
    const float* Wec2 = (const float*)d_in[28];
    const float* bec2 = (const float*)d_in[29];
    const float* Wfc1 = (const float*)d_in[30];
    const float* bfc1 = (const float*)d_in[31];
    const float* Wfc2 = (const float*)d_in[32];
    const float* bfc2 = (const float*)d_in[33];
    const float* Wec3 = (const float*)d_in[34];
    const float* bec3 = (const float*)d_in[35];

    float* ws = (float*)d_ws;
    float* n1 = ws + F_N1;
    float* n2 = ws + F_N2;
    float* aN_val = ws + F_ANVAL;
    float* row_val = ws + F_ROWVAL;
    float* col_sum = ws + F_COLSUM;
    float* inv_cs = ws + F_INVCS;
    float* aT_val = ws + F_ATVAL;
    int* aN_idx = (int*)(ws + I_ANIDX);
    int* row_idx = (int*)(ws + I_ROWIDX);
    int* col_cnt = (int*)(ws + I_COLCNT);
    int* col_off = (int*)(ws + I_COLOFF);
    int* col_fill = (int*)(ws + I_COLFILL);
    int* aT_idx = (int*)(ws + I_ATIDX);

    // pick largest batch-chunk CB that fits the workspace
    size_t avail = ws_size / 4;   // floats
    int CB = 8;
    while (CB > 1 && GRAPH_FLOATS + (size_t)CB * PB_TOTAL > avail) CB >>= 1;
    int nchunk = 8 / CB;

    float* gated = ws + GRAPH_FLOATS;
    float* hd_emb = gated + (size_t)CB * PB_GATED;
    float* xs = hd_emb + (size_t)CB * PB_HD;
    float* h1 = xs + (size_t)CB * PB_XS;
    float* h2 = h1 + (size_t)CB * PB_XS;
    float* mix = h2 + (size_t)CB * PB_XS;
    float* eco = xs;    // alias: xs+h1 region >= eco
    float* fbuf = h2;   // alias: h2 dead by k_fc

    // ---- graph construction (once) ----
    k_init<<<4, 256, 0, stream>>>(col_cnt, col_fill, col_sum);
    k_embed<<<320, 256, 0, stream>>>(gc_emb1, gc_emb2, gc_w1, gc_b1, gc_w2, gc_b2, n1, n2);
    k_adj<<<1024, 256, 0, stream>>>(n1, n2, aN_val, aN_idx, row_val, row_idx, col_cnt, col_sum);
    k_scan<<<1, 1024, 0, stream>>>(col_cnt, col_off, col_sum, inv_cs);
    k_scatter<<<40, 256, 0, stream>>>(row_idx, row_val, col_off, col_fill, aT_idx, aT_val);

    // ---- per-chunk pipeline ----
    for (int ch = 0; ch < nchunk; ch++) {
        const float* hist_c = hist + (size_t)ch * CB * ROWS_PER_B * 4;
        float* out_c = (float*)d_out + (size_t)ch * CB * ROWS_PER_B;

        k_gate<<<CB * 3072, 256, 0, stream>>>(hist_c, node_emb_u, T_i_D_emb, D_i_W_emb,
                                              Wg1, bg1, Wg2, bg2, W_emb, b_emb, gated, hd_emb);
        for (int xp = 0; xp < 2; xp++) {
            k_wsc<<<CB * 256, 256, 0, stream>>>(gated, Wsc, bsc, xs, xp * 64);
            for (int cp = 0; cp < 2; cp++) {
                k_spmm<<<CB * 2048, 256, 0, stream>>>(h1, xs, xs, aN_idx, aN_val, aT_idx, aT_val,
                                                      col_off, inv_cs, cp);
                k_spmm<<<CB * 2048, 256, 0, stream>>>(h2, xs, h1, aN_idx, aN_val, aT_idx, aT_val,
                                                      col_off, inv_cs, cp);
                k_proj<<<CB * 1024, 256, 0, stream>>>(xs, h1, h2, cp ? mix2_w : mix1_w,
                                                      mix1_b, mix2_b, mix, xp, cp);
            }
        }
        k_tf<<<CB * 1024, 256, 0, stream>>>(mix, Wtf1, btf1, Wtf2, btf2);
        k_ec<<<CB * 1024, 256, 0, stream>>>(mix, Wec1, bec1, Wec2, bec2, eco);
        k_fc<<<CB * 768, 256, 0, stream>>>(gated, eco, hd_emb, hist_c, T_i_D_emb, D_i_W_emb,
                                           Wfc1, bfc1, Wfc2, bfc2, fbuf);
        k_ec3<<<CB * 48, 256, 0, stream>>>(fbuf, Wec3, bec3, out_c);
    }
}